// Round 5
// baseline (151.738 us; speedup 1.0000x reference)
//
#include <hip/hip_runtime.h>
#include <hip/hip_bf16.h>

#define ALPHA 0.2f

constexpr int B = 8, N = 2048, F = 64;

typedef __attribute__((ext_vector_type(8))) short bf16x8;
typedef __attribute__((ext_vector_type(16))) float f32x16;

__device__ __forceinline__ float lrelu(float x) { return fmaxf(x, ALPHA * x); }

// ---------------- K1: h = inp@W ; f1 = h@a1 ; f2 = h@a2 ; hT (bf16, transposed,
//                   PRE-XOR-SWIZZLED within each 128-col tile for k3's glds path)
__global__ __launch_bounds__(256) void k1_project(
    const float* __restrict__ inp, const float* __restrict__ W,
    const float* __restrict__ a,
    __hip_bfloat16* __restrict__ hT, float* __restrict__ f1, float* __restrict__ f2)
{
  __shared__ float Wl[64][64];
  __shared__ float inpl[32][64];
  __shared__ float red[32][8][2];
  __shared__ __hip_bfloat16 hl[32][64];
  __shared__ float al[128];

  const int tid = threadIdx.x;
  const int g0 = blockIdx.x * 32;
  const int b = g0 / N, i0 = g0 % N;

  #pragma unroll
  for (int m = 0; m < 4; ++m) {
    int off = m * 1024 + tid * 4;
    *(float4*)((float*)Wl + off) = *(const float4*)(W + off);
  }
  #pragma unroll
  for (int m = 0; m < 2; ++m) {
    int off = m * 1024 + tid * 4;
    *(float4*)((float*)inpl + off) = *(const float4*)(inp + (size_t)g0 * F + off);
  }
  if (tid < 128) al[tid] = a[tid];
  __syncthreads();

  const int r = tid >> 3, c0 = (tid & 7) * 8;
  float acc[8];
  #pragma unroll
  for (int c = 0; c < 8; ++c) acc[c] = 0.f;
  for (int k = 0; k < 64; ++k) {
    float v = inpl[r][k];
    #pragma unroll
    for (int c = 0; c < 8; ++c) acc[c] += v * Wl[k][c0 + c];
  }
  float p1 = 0.f, p2 = 0.f;
  unsigned short hb[8] __attribute__((aligned(16)));
  #pragma unroll
  for (int c = 0; c < 8; ++c) {
    p1 += acc[c] * al[c0 + c];
    p2 += acc[c] * al[64 + c0 + c];
    __hip_bfloat16 hv = __float2bfloat16(acc[c]);
    hb[c] = *(unsigned short*)&hv;
  }
  red[r][tid & 7][0] = p1;
  red[r][tid & 7][1] = p2;
  *(uint4*)&hl[r][c0] = *(uint4*)hb;
  __syncthreads();

  if (tid < 32) {
    float s1 = 0.f, s2 = 0.f;
    #pragma unroll
    for (int m = 0; m < 8; ++m) { s1 += red[tid][m][0]; s2 += red[tid][m][1]; }
    f1[g0 + tid] = s1;
    f2[g0 + tid] = s2;
  }
  const int c = tid >> 2, r8 = (tid & 3) * 8;
  unsigned short tb[8] __attribute__((aligned(16)));
  #pragma unroll
  for (int m = 0; m < 8; ++m) tb[m] = *(unsigned short*)&hl[r8 + m][c];
  const int jb = i0 + r8;
  const int jsw = (jb & ~127) | ((jb & 127) ^ ((c & 7) << 3));
  *(uint4*)(hT + ((size_t)b * F + c) * N + jsw) = *(uint4*)tb;
}

// ---------------- K2: per-batch unmasked max of f2 (upper bound for row max)
__global__ __launch_bounds__(256) void k2_f2max(const float* __restrict__ f2,
                                                float* __restrict__ f2max)
{
  __shared__ float s[256];
  const int b = blockIdx.x, tid = threadIdx.x;
  float m = -1e30f;
  for (int j = tid; j < N; j += 256) m = fmaxf(m, f2[b * N + j]);
  s[tid] = m;
  __syncthreads();
  for (int w = 128; w > 0; w >>= 1) {
    if (tid < w) s[tid] = fmaxf(s[tid], s[tid + w]);
    __syncthreads();
  }
  if (tid == 0) f2max[b] = s[0];
}

// ---------------- K3: DIAGNOSTIC build — 3 dummy passes (kept alive, laundered
// pointers, results discarded) + 1 real pass. Output identical to round 4.
__global__ __launch_bounds__(256) void k3_attn(
    const int* __restrict__ adj, const __hip_bfloat16* __restrict__ hT,
    const float* __restrict__ f1, const float* __restrict__ f2,
    const float* __restrict__ f2max, float* __restrict__ out)
{
  constexpr int RT = 32, JT = 128, NT = N / JT;  // 16 tiles
  __shared__ __hip_bfloat16 Pl[2][RT][JT];   // 16KB (XOR-swizzled)
  __shared__ __hip_bfloat16 Hl[2][F][JT];    // 32KB (linear; global pre-swizzled)
  __shared__ float rs[RT][8];                // 1KB
  __shared__ float rcp_s[RT];
  __shared__ float redt[2][32][32];          // 8KB

  const int tid = threadIdx.x;
  const int lane = tid & 63, wid = tid >> 6;
  const int ct = wid >> 1, kh = wid & 1;
  const int bi = blockIdx.x;
  const int b = bi / (N / RT);
  const int i0 = (bi % (N / RT)) * RT;

  const int r = tid >> 3, q = tid & 7;
  const float f1r = f1[b * N + i0 + r];
  const float Mr = lrelu(f1r + f2max[b]);    // >= true masked row max (lrelu monotone)

  const int* adjrow = adj + ((size_t)(b * N + i0 + r)) * N + 4 * q;
  const float* f2base = f2 + b * N + 4 * q;
  const int swp = (r & 7) << 3;

  const __hip_bfloat16* hsrc =
      hT + ((size_t)b * F + (wid * 16 + (lane >> 4))) * N + (lane & 15) * 8;

  const int arow = lane & 31;
  const int bcol = ct * 32 + (lane & 31);
  const int klo = kh * 64 + ((lane >> 5) * 8);

  #define STAGE_H(HS, T, BUFI)                                                  \
    do {                                                                        \
      const __hip_bfloat16* s0_ = (HS) + (T) * JT;                              \
      char* lb_ = (char*)(&Hl[(BUFI)][0][0]) + wid * 4096;                      \
      _Pragma("unroll")                                                         \
      for (int q_ = 0; q_ < 4; ++q_) {                                          \
        __builtin_amdgcn_global_load_lds(                                       \
            (const __attribute__((address_space(1))) void*)(s0_ + q_ * 4 * N),  \
            (__attribute__((address_space(3))) void*)(lb_ + q_ * 1024),         \
            16, 0, 0);                                                          \
      }                                                                         \
    } while (0)

  #define LOADSET(ADJR, F2B, AV, FV, T)                                         \
    do {                                                                        \
      _Pragma("unroll")                                                         \
      for (int m_ = 0; m_ < 4; ++m_) {                                          \
        AV[m_] = *(const int4*)((ADJR) + (T) * JT + 32 * m_);                   \
        FV[m_] = *(const float4*)((F2B) + (T) * JT + 32 * m_);                  \
      }                                                                         \
    } while (0)

  #define ITER(ADJR, F2B, HS, T, AV, FV, BUF, VM, DO_STAGE, DO_LOAD, ACC, RS_)  \
    do {                                                                        \
      _Pragma("unroll")                                                         \
      for (int m_ = 0; m_ < 4; ++m_) {                                          \
        const int* ai_ = (const int*)&AV[m_];                                   \
        const float* fe_ = (const float*)&FV[m_];                               \
        unsigned short pbm_[4] __attribute__((aligned(8)));                     \
        _Pragma("unroll")                                                       \
        for (int e_ = 0; e_ < 4; ++e_) {                                        \
          float s_ = lrelu(f1r + fe_[e_]);                                      \
          float p_ = (ai_[e_] > 0) ? __expf(s_ - Mr) : 0.f;                     \
          __hip_bfloat16 pbf_ = __float2bfloat16(p_);                           \
          RS_ += __bfloat162float(pbf_);                                        \
          pbm_[e_] = *(unsigned short*)&pbf_;                                   \
        }                                                                       \
        *(uint2*)&Pl[BUF][r][(4 * q + 32 * m_) ^ swp] = *(uint2*)pbm_;          \
      }                                                                         \
      asm volatile("s_waitcnt vmcnt(" #VM ") lgkmcnt(0)" ::: "memory");         \
      __builtin_amdgcn_s_barrier();                                             \
      __builtin_amdgcn_sched_barrier(0);                                        \
      if (DO_STAGE) STAGE_H(HS, (T) + 1, (BUF) ^ 1);                            \
      __builtin_amdgcn_sched_barrier(0);                                        \
      if (DO_LOAD) LOADSET(ADJR, F2B, AV, FV, (T) + 2);                         \
      __builtin_amdgcn_sched_barrier(0);                                        \
      __builtin_amdgcn_s_setprio(1);                                            \
      _Pragma("unroll")                                                         \
      for (int s_ = 0; s_ < 4; ++s_) {                                          \
        const int ak_ = klo + s_ * 16;                                          \
        bf16x8 af_ = *(const bf16x8*)&Pl[BUF][arow][ak_ ^ ((arow & 7) << 3)];   \
        bf16x8 bf_ = *(const bf16x8*)&Hl[BUF][bcol][ak_ ^ ((bcol & 7) << 3)];   \
        asm volatile("v_mfma_f32_32x32x16_bf16 %0, %1, %2, %0"                  \
                     : "+v"(ACC) : "v"(af_), "v"(bf_));                         \
      }                                                                         \
      __builtin_amdgcn_s_setprio(0);                                            \
    } while (0)

  #define RUN_PASS(ADJR, F2B, HS, ACC, RS_)                                     \
    do {                                                                        \
      int4 pa0[4], pa1[4]; float4 pf0[4], pf1[4];                               \
      STAGE_H(HS, 0, 0);                                                        \
      __builtin_amdgcn_sched_barrier(0);                                        \
      LOADSET(ADJR, F2B, pa0, pf0, 0);                                          \
      LOADSET(ADJR, F2B, pa1, pf1, 1);                                          \
      for (int t_ = 0; t_ < NT - 2; t_ += 2) {                                  \
        ITER(ADJR, F2B, HS, t_,     pa0, pf0, 0, 8, true, true, ACC, RS_);      \
        ITER(ADJR, F2B, HS, t_ + 1, pa1, pf1, 1, 8, true, true, ACC, RS_);      \
      }                                                                         \
      ITER(ADJR, F2B, HS, NT - 2, pa0, pf0, 0, 8, true,  false, ACC, RS_);      \
      ITER(ADJR, F2B, HS, NT - 1, pa1, pf1, 1, 0, false, false, ACC, RS_);      \
    } while (0)

  // ---- 3 dummy passes: same work, laundered pointers, results discarded ----
  f32x16 acc2; float rowsum2 = 0.f;
  #pragma unroll
  for (int z = 0; z < 16; ++z) acc2[z] = 0.f;
  #pragma unroll 1
  for (int rep = 0; rep < 3; ++rep) {
    const int* adj_d = adjrow;
    const float* f2_d = f2base;
    const __hip_bfloat16* h_d = hsrc;
    asm volatile("" : "+v"(adj_d));
    asm volatile("" : "+v"(f2_d));
    asm volatile("" : "+v"(h_d));
    RUN_PASS(adj_d, f2_d, h_d, acc2, rowsum2);
  }
  #pragma unroll
  for (int z = 0; z < 16; ++z) { float tz = acc2[z]; asm volatile("" :: "v"(tz)); }
  { float tz = rowsum2; asm volatile("" :: "v"(tz)); }
  __builtin_amdgcn_s_barrier();

  // ---- real pass ----
  float rowsum = 0.f;
  f32x16 acc;
  #pragma unroll
  for (int z = 0; z < 16; ++z) acc[z] = 0.f;
  RUN_PASS(adjrow, f2base, hsrc, acc, rowsum);
  #undef RUN_PASS
  #undef ITER
  #undef LOADSET
  #undef STAGE_H

  rs[r][q] = rowsum;
  if (kh == 1) {
    #pragma unroll
    for (int z = 0; z < 16; ++z)
      redt[ct][(z & 3) + 8 * (z >> 2) + 4 * (lane >> 5)][lane & 31] = acc[z];
  }
  __syncthreads();
  if (tid < 32) {
    float s = 0.f;
    #pragma unroll
    for (int m = 0; m < 8; ++m) s += rs[tid][m];
    rcp_s[tid] = 1.0f / fmaxf(s, 1e-30f);
  }
  __syncthreads();
  if (kh == 0) {
    #pragma unroll
    for (int z = 0; z < 16; ++z) {
      const int row = (z & 3) + 8 * (z >> 2) + 4 * (lane >> 5);
      float v = (acc[z] + redt[ct][row][lane & 31]) * rcp_s[row];
      v = v > 0.f ? v : expm1f(v);
      out[((size_t)(b * N + i0 + row)) * F + ct * 32 + (lane & 31)] = v;
    }
  }
}

extern "C" void kernel_launch(void* const* d_in, const int* in_sizes, int n_in,
                              void* d_out, int out_size, void* d_ws, size_t ws_size,
                              hipStream_t stream) {
  const float* inp = (const float*)d_in[0];
  const int*   adj = (const int*)d_in[1];
  const float* W   = (const float*)d_in[2];
  const float* a   = (const float*)d_in[3];
  float* out = (float*)d_out;

  char* ws = (char*)d_ws;
  __hip_bfloat16* hT = (__hip_bfloat16*)ws;
  float* f1  = (float*)(ws + (size_t)B * F * N * sizeof(__hip_bfloat16));
  float* f2  = f1 + (size_t)B * N;
  float* f2m = f2 + (size_t)B * N;

  hipLaunchKernelGGL(k1_project, dim3(B * N / 32), dim3(256), 0, stream, inp, W, a, hT, f1, f2);
  hipLaunchKernelGGL(k2_f2max, dim3(B), dim3(256), 0, stream, f2, f2m);
  hipLaunchKernelGGL(k3_attn, dim3(B * N / 32), dim3(256), 0, stream, adj, hT, f1, f2, f2m, out);
}

// Round 7
// 61.846 us; speedup vs baseline: 2.4535x; 2.4535x over previous
//
#include <hip/hip_runtime.h>
#include <hip/hip_bf16.h>

#define ALPHA 0.2f

constexpr int B = 8, N = 2048, F = 64;

typedef __attribute__((ext_vector_type(8))) short bf16x8;
typedef __attribute__((ext_vector_type(4))) float f32x4;

__device__ __forceinline__ float lrelu(float x) { return fmaxf(x, ALPHA * x); }

// ---------------- K0: init f2max to -inf (atomic-max target)
__global__ void k0_init(float* __restrict__ f2m) {
  if (threadIdx.x < B) ((int*)f2m)[threadIdx.x] = 0xFF800000;  // -inf bits
}

// ---------------- K1: h = inp@W ; f1 ; f2 ; hT (bf16, transposed, pre-swizzled)
//                   + per-batch f2max via signed float atomic-max trick
__global__ __launch_bounds__(256) void k1_project(
    const float* __restrict__ inp, const float* __restrict__ W,
    const float* __restrict__ a,
    __hip_bfloat16* __restrict__ hT, float* __restrict__ f1, float* __restrict__ f2,
    float* __restrict__ f2m)
{
  __shared__ float Wl[64][64];
  __shared__ float inpl[32][64];
  __shared__ float red[32][8][2];
  __shared__ __hip_bfloat16 hl[32][64];
  __shared__ float al[128];

  const int tid = threadIdx.x;
  const int g0 = blockIdx.x * 32;
  const int b = g0 / N, i0 = g0 % N;

  #pragma unroll
  for (int m = 0; m < 4; ++m) {
    int off = m * 1024 + tid * 4;
    *(float4*)((float*)Wl + off) = *(const float4*)(W + off);
  }
  #pragma unroll
  for (int m = 0; m < 2; ++m) {
    int off = m * 1024 + tid * 4;
    *(float4*)((float*)inpl + off) = *(const float4*)(inp + (size_t)g0 * F + off);
  }
  if (tid < 128) al[tid] = a[tid];
  __syncthreads();

  const int r = tid >> 3, c0 = (tid & 7) * 8;
  float acc[8];
  #pragma unroll
  for (int c = 0; c < 8; ++c) acc[c] = 0.f;
  for (int k = 0; k < 64; ++k) {
    float v = inpl[r][k];
    #pragma unroll
    for (int c = 0; c < 8; ++c) acc[c] += v * Wl[k][c0 + c];
  }
  float p1 = 0.f, p2 = 0.f;
  unsigned short hb[8] __attribute__((aligned(16)));
  #pragma unroll
  for (int c = 0; c < 8; ++c) {
    p1 += acc[c] * al[c0 + c];
    p2 += acc[c] * al[64 + c0 + c];
    __hip_bfloat16 hv = __float2bfloat16(acc[c]);
    hb[c] = *(unsigned short*)&hv;
  }
  red[r][tid & 7][0] = p1;
  red[r][tid & 7][1] = p2;
  *(uint4*)&hl[r][c0] = *(uint4*)hb;
  __syncthreads();

  if (tid < 32) {
    float s1 = 0.f, s2 = 0.f;
    #pragma unroll
    for (int m = 0; m < 8; ++m) { s1 += red[tid][m][0]; s2 += red[tid][m][1]; }
    f1[g0 + tid] = s1;
    f2[g0 + tid] = s2;
    // block max of s2 -> one atomic per block
    float mx = s2;
    #pragma unroll
    for (int w = 16; w >= 1; w >>= 1) mx = fmaxf(mx, __shfl_xor(mx, w, 32));
    if (tid == 0) {
      if (mx >= 0.f) atomicMax((int*)&f2m[b], __float_as_int(mx));
      else atomicMin((unsigned int*)&f2m[b], (unsigned int)__float_as_int(mx));
    }
  }
  const int c = tid >> 2, r8 = (tid & 3) * 8;
  unsigned short tb[8] __attribute__((aligned(16)));
  #pragma unroll
  for (int m = 0; m < 8; ++m) tb[m] = *(unsigned short*)&hl[r8 + m][c];
  const int jb = i0 + r8;
  const int jsw = (jb & ~127) | ((jb & 127) ^ ((c & 7) << 3));
  *(uint4*)(hT + ((size_t)b * F + c) * N + jsw) = *(uint4*)tb;
}

// ---------------- K3: fused mask + softmax + PV + elu
// 8 waves (512 thr), 16x16x32 MFMA, one output tile per wave (full K -> no
// cross-wave reduction). LDS ~50KB -> 2-3 blocks/CU (16-24 waves).
// Counted vmcnt(4): 2 glds drained, 4 adj/f2 prefetches stay in flight.
// glds SOURCE is LINEAR (hT is pre-swizzled by k1); swizzle applied on read only.
__global__ __launch_bounds__(512, 4) void k3_attn(
    const int* __restrict__ adj, const __hip_bfloat16* __restrict__ hT,
    const float* __restrict__ f1, const float* __restrict__ f2,
    const float* __restrict__ f2max, float* __restrict__ out)
{
  constexpr int RT = 32, JT = 128, NT = N / JT;  // 16 tiles
  __shared__ __hip_bfloat16 Pl[2][RT][JT];   // 16KB (XOR-swizzled)
  __shared__ __hip_bfloat16 Hl[2][F][JT];    // 32KB (content pre-swizzled)
  __shared__ float rs[RT][16];               // 2KB
  __shared__ float rcp_s[RT];

  const int tid = threadIdx.x;
  const int lane = tid & 63, wid = tid >> 6;       // 8 waves
  const int rt = (wid >> 2) * 16, ctb = (wid & 3) * 16;  // wave's 16x16 out tile
  const int bi = blockIdx.x;
  const int b = bi / (N / RT);
  const int i0 = (bi % (N / RT)) * RT;

  // score mapping: 16 threads per row; thread q owns j in {4q+64m : m=0,1}
  const int r = tid >> 4, q = tid & 15;
  const float f1r = f1[b * N + i0 + r];
  const float Mr = lrelu(f1r + f2max[b]);    // >= true masked row max (lrelu monotone)

  const int* adjrow = adj + ((size_t)(b * N + i0 + r)) * N + 4 * q;
  const float* f2base = f2 + b * N + 4 * q;
  const int swp = (r & 7) << 3;

  // glds: wave wid stages feature rows [wid*8, wid*8+8); 2 issues x 4 rows.
  // LINEAR source offsets — hT content is already swizzled.
  const int hr0 = lane >> 4;                               // 0..3
  const __hip_bfloat16* hsrc0 =
      hT + ((size_t)b * F + wid * 8 + hr0) * N + (lane & 15) * 8;
  const __hip_bfloat16* hsrc1 =
      hT + ((size_t)b * F + wid * 8 + 4 + hr0) * N + (lane & 15) * 8;

  float rowsum = 0.f;
  f32x4 acc = {0.f, 0.f, 0.f, 0.f};

  const int arow = rt + (lane & 15);     // P row for A-frag
  const int bcol = ctb + (lane & 15);    // Hl feature row for B-frag
  const int kgrp = (lane >> 4) * 8;      // per-lane k offset within K=32 step

  #define STAGE_H(T, BUFI)                                                      \
    do {                                                                        \
      char* lb_ = (char*)(&Hl[(BUFI)][0][0]) + wid * 2048;                      \
      __builtin_amdgcn_global_load_lds(                                         \
          (const __attribute__((address_space(1))) void*)(hsrc0 + (T) * JT),    \
          (__attribute__((address_space(3))) void*)(lb_), 16, 0, 0);            \
      __builtin_amdgcn_global_load_lds(                                         \
          (const __attribute__((address_space(1))) void*)(hsrc1 + (T) * JT),    \
          (__attribute__((address_space(3))) void*)(lb_ + 1024), 16, 0, 0);     \
    } while (0)

  #define LOADSET(AV, FV, T)                                                    \
    do {                                                                        \
      _Pragma("unroll")                                                         \
      for (int m_ = 0; m_ < 2; ++m_) {                                          \
        AV[m_] = *(const int4*)(adjrow + (T) * JT + 64 * m_);                   \
        FV[m_] = *(const float4*)(f2base + (T) * JT + 64 * m_);                 \
      }                                                                         \
    } while (0)

  #define ITER(T, AV, FV, BUF, VM, DO_STAGE, DO_LOAD)                           \
    do {                                                                        \
      _Pragma("unroll")                                                         \
      for (int m_ = 0; m_ < 2; ++m_) {                                          \
        const int* ai_ = (const int*)&AV[m_];                                   \
        const float* fe_ = (const float*)&FV[m_];                               \
        unsigned short pbm_[4] __attribute__((aligned(8)));                     \
        _Pragma("unroll")                                                       \
        for (int e_ = 0; e_ < 4; ++e_) {                                        \
          float s_ = lrelu(f1r + fe_[e_]);                                      \
          float p_ = (ai_[e_] > 0) ? __expf(s_ - Mr) : 0.f;                     \
          __hip_bfloat16 pbf_ = __float2bfloat16(p_);                           \
          rowsum += __bfloat162float(pbf_);                                     \
          pbm_[e_] = *(unsigned short*)&pbf_;                                   \
        }                                                                       \
        *(uint2*)&Pl[BUF][r][(4 * q + 64 * m_) ^ swp] = *(uint2*)pbm_;          \
      }                                                                         \
      asm volatile("s_waitcnt vmcnt(" #VM ") lgkmcnt(0)" ::: "memory");         \
      __builtin_amdgcn_s_barrier();                                             \
      __builtin_amdgcn_sched_barrier(0);                                        \
      if (DO_STAGE) STAGE_H((T) + 1, (BUF) ^ 1);                                \
      __builtin_amdgcn_sched_barrier(0);                                        \
      if (DO_LOAD) LOADSET(AV, FV, (T) + 2);                                    \
      __builtin_amdgcn_sched_barrier(0);                                        \
      __builtin_amdgcn_s_setprio(1);                                            \
      _Pragma("unroll")                                                         \
      for (int s_ = 0; s_ < 4; ++s_) {                                          \
        const int ak_ = s_ * 32 + kgrp;                                         \
        bf16x8 af_ = *(const bf16x8*)&Pl[BUF][arow][ak_ ^ ((arow & 7) << 3)];   \
        bf16x8 bf_ = *(const bf16x8*)&Hl[BUF][bcol][ak_ ^ ((bcol & 7) << 3)];   \
        asm volatile("v_mfma_f32_16x16x32_bf16 %0, %1, %2, %0"                  \
                     : "+v"(acc) : "v"(af_), "v"(bf_));                         \
      }                                                                         \
      __builtin_amdgcn_s_setprio(0);                                            \
    } while (0)

  // prologue: glds(0) first (oldest), then reg tiles 0,1
  int4 a0v[2], a1v[2]; float4 g0v[2], g1v[2];
  STAGE_H(0, 0);
  __builtin_amdgcn_sched_barrier(0);
  LOADSET(a0v, g0v, 0);
  LOADSET(a1v, g1v, 1);

  for (int t = 0; t < NT - 2; t += 2) {
    ITER(t,     a0v, g0v, 0, 4, true, true);
    ITER(t + 1, a1v, g1v, 1, 4, true, true);
  }
  ITER(NT - 2, a0v, g0v, 0, 4, true,  false);
  ITER(NT - 1, a1v, g1v, 1, 0, false, false);
  #undef ITER
  #undef LOADSET
  #undef STAGE_H

  rs[r][q] = rowsum;
  __syncthreads();
  if (tid < 32) {
    float s = 0.f;
    #pragma unroll
    for (int m = 0; m < 16; ++m) s += rs[tid][m];
    rcp_s[tid] = 1.0f / fmaxf(s, 1e-30f);
  }
  __syncthreads();
  {
    const int orow0 = rt + (lane >> 4) * 4;   // C/D: col=lane&15, row=(lane>>4)*4+z
    const int ocol = ctb + (lane & 15);
    #pragma unroll
    for (int z = 0; z < 4; ++z) {
      const int row = orow0 + z;
      float v = acc[z] * rcp_s[row];
      v = v > 0.f ? v : expm1f(v);
      out[((size_t)(b * N + i0 + row)) * F + ocol] = v;
    }
  }
}

extern "C" void kernel_launch(void* const* d_in, const int* in_sizes, int n_in,
                              void* d_out, int out_size, void* d_ws, size_t ws_size,
                              hipStream_t stream) {
  const float* inp = (const float*)d_in[0];
  const int*   adj = (const int*)d_in[1];
  const float* W   = (const float*)d_in[2];
  const float* a   = (const float*)d_in[3];
  float* out = (float*)d_out;

  char* ws = (char*)d_ws;
  __hip_bfloat16* hT = (__hip_bfloat16*)ws;
  float* f1  = (float*)(ws + (size_t)B * F * N * sizeof(__hip_bfloat16));
  float* f2  = f1 + (size_t)B * N;
  float* f2m = f2 + (size_t)B * N;

  hipLaunchKernelGGL(k0_init, dim3(1), dim3(64), 0, stream, f2m);
  hipLaunchKernelGGL(k1_project, dim3(B * N / 32), dim3(256), 0, stream,
                     inp, W, a, hT, f1, f2, f2m);
  hipLaunchKernelGGL(k3_attn, dim3(B * N / 32), dim3(512), 0, stream,
                     adj, hT, f1, f2, f2m, out);
}